// Round 14
// baseline (426.020 us; speedup 1.0000x reference)
//
#include <hip/hip_runtime.h>

#define HW (128*128)

typedef __bf16 bf16x8 __attribute__((ext_vector_type(8)));
typedef float  float4v __attribute__((ext_vector_type(4)));
typedef int    int4v   __attribute__((ext_vector_type(4)));

static __device__ __forceinline__ short f2bf(float f) {
    unsigned u = __float_as_uint(f);
    unsigned r = (u + 0x7FFFu + ((u >> 16) & 1u)) >> 16;
    return (short)(r & 0xFFFFu);
}
static __device__ __forceinline__ int pack2(short a, short b) {
    return (int)((unsigned short)a | ((unsigned)(unsigned short)b << 16));
}
// async global->LDS, 16B per lane; LDS dest = wave-uniform base + lane*16
static __device__ __forceinline__ void async_cp16(const void* g, void* l) {
    __builtin_amdgcn_global_load_lds(
        (const __attribute__((address_space(1))) unsigned int*)g,
        (__attribute__((address_space(3))) unsigned int*)l, 16, 0, 0);
}

// ---------------------------------------------------------------------------
// prep: weight repacks + h2p halo zeroing (unchanged from R13).
// ---------------------------------------------------------------------------
__global__ __launch_bounds__(256) void prep_weights(
    const float* __restrict__ W1, const float* __restrict__ W2,
    const float* __restrict__ W3,
    short* __restrict__ W1g, short* __restrict__ W2g, short* __restrict__ W3g,
    char* __restrict__ h2p)
{
    int tid = blockIdx.x * 256 + threadIdx.x;
    int stride = gridDim.x * 256;
    for (int i = tid; i < 10240; i += stride) {
        int e = i & 7, ch = (i >> 3) & 63, sq = i >> 9;   // sq 0..19
        int s = sq >> 2, quad = sq & 3;
        int k = s*32 + quad*8 + e;
        int tap = k >> 4, ci = k & 15;
        float v = 0.f;
        if (tap < 9) {
            int ky = (tap*11) >> 5; int kx = tap - 3*ky;
            v = W1[((ch*16 + ci)*3 + ky)*3 + kx];
        }
        W1g[i] = f2bf(v);
    }
    for (int i = tid; i < 4096; i += stride) {
        int e = i & 7, ch = (i >> 3) & 63, sq = i >> 9;   // sq 0..7
        int s = sq >> 2, quad = sq & 3;
        int k = s*32 + quad*8 + e;
        W2g[i] = f2bf(W2[ch*64 + k]);
    }
    // W3g: flat i = ((tap*8 + ks*4 + quad)*288 + n)*8 + e
    for (int i = tid; i < 165888; i += stride) {
        int e = i & 7;
        int n = (i >> 3) % 288;
        int r2 = i / 2304;
        int quad = r2 & 3;
        int ks = (r2 >> 2) & 1;
        int tap = r2 >> 3;
        int ch = n / 24, jj = n - 24*ch;
        int kk = ks*32 + quad*8 + e;
        float v = 0.f;
        if (jj < 23) v = W3[((ch*23 + jj)*64 + kk)*9 + tap];
        W3g[i] = f2bf(v);
    }
    // h2p halo zero: 16 batches x 516 border px x 8 chunks
    for (int i = tid; i < 16*516*8; i += stride) {
        int cchunk = i & 7, pxi = (i >> 3) % 516, b = i / (516*8);
        int yy, xx;
        if (pxi < 130)      { yy = 0;   xx = pxi; }
        else if (pxi < 260) { yy = 129; xx = pxi - 130; }
        else if (pxi < 388) { yy = pxi - 260 + 1; xx = 0; }
        else                { yy = pxi - 388 + 1; xx = 129; }
        int4v zz = {0,0,0,0};
        *(int4v*)(h2p + (size_t)((b*130 + yy)*130 + xx)*128 + cchunk*16) = zz;
    }
}

// ---------------------------------------------------------------------------
// pack z with 1-px halo; initialize logdet output from logdet input.
// ---------------------------------------------------------------------------
__global__ __launch_bounds__(256) void pack_z(
    const float* __restrict__ x, const float* __restrict__ cond,
    const float* __restrict__ ld_in,
    short* __restrict__ zp, float* __restrict__ ldout)
{
    int id = blockIdx.x * 256 + threadIdx.x;
    if (id < 16) ldout[id] = ld_in[id];
    if (id >= 16*130*130) return;
    int b = id / 16900;
    int rem = id - b*16900;
    int yy = rem / 130;
    int xx = rem - yy*130;
    short vs[16];
    #pragma unroll
    for (int c = 0; c < 16; ++c) vs[c] = 0;
    if (yy >= 1 && yy <= 128 && xx >= 1 && xx <= 128) {
        int pix = (yy - 1)*128 + (xx - 1);
        bool frozen = ((yy + xx) & 1) == 1;
        #pragma unroll
        for (int c = 0; c < 12; ++c)
            vs[c] = f2bf(frozen ? x[(b*12 + c)*HW + pix] : 0.f);
        #pragma unroll
        for (int c = 0; c < 4; ++c)
            vs[12 + c] = f2bf(cond[(b*4 + c)*HW + pix]);
    }
    int4v lo = { pack2(vs[0],vs[1]),  pack2(vs[2],vs[3]),
                 pack2(vs[4],vs[5]),  pack2(vs[6],vs[7]) };
    int4v hi = { pack2(vs[8],vs[9]),  pack2(vs[10],vs[11]),
                 pack2(vs[12],vs[13]),pack2(vs[14],vs[15]) };
    *(int4v*)(zp + id*16)     = lo;
    *(int4v*)(zp + id*16 + 8) = hi;
}

// ---------------------------------------------------------------------------
// fused conv1 (3x3, 16->64) + conv2 (1x1, 64->64) — hybrid paths, ONE barrier.
// (Unchanged from R13.)
// ---------------------------------------------------------------------------
__global__ __launch_bounds__(256, 4) void conv12_kernel(
    const char* __restrict__ zp, const char* __restrict__ W1g,
    const char* __restrict__ W2g,
    const float* __restrict__ b1, const float* __restrict__ b2,
    char* __restrict__ h2p)
{
    __shared__ __align__(16) char smem[28928];
    int t = threadIdx.x;
    int lane = t & 63, w = t >> 6;
    int l15 = lane & 15, quad = lane >> 4;
    int bid = blockIdx.x;
    int b = bid & 15, y = bid >> 4;
    int pxb = w << 5;

    const char* zb = (const char*)zp + ((size_t)(b*16900) + (size_t)y*130)*32;
    #pragma unroll
    for (int ii = 0; ii < 4; ++ii) {
        int q = t + ii*256;
        if (q < 780)
            async_cp16(zb + (q << 4),
                smem + (unsigned)__builtin_amdgcn_readfirstlane(
                            ((w << 6) + ii*256) << 4) + (lane << 4));
    }
    __syncthreads();

    const float4v z4 = {0.f,0.f,0.f,0.f};
    char* ht = smem + 12544 + (w << 12);

    float4v acc1[4][2];
    #pragma unroll
    for (int i = 0; i < 4; ++i)
        #pragma unroll
        for (int j = 0; j < 2; ++j) acc1[i][j] = z4;

    for (int s = 0; s < 5; ++s) {
        const char* ap = W1g + (((s*4 + quad)*64 + l15) << 4);
        bf16x8 aw[4];
        #pragma unroll
        for (int i = 0; i < 4; ++i)
            aw[i] = *(const bf16x8*)(ap + (i << 8));
        int tap = 2*s + (quad >> 1);
        int tapc = tap > 8 ? 8 : tap;
        int ty = (tapc*11) >> 5;
        int tx = tapc - 3*ty;
        #pragma unroll
        for (int j = 0; j < 2; ++j) {
            int px = pxb + j*16 + l15 + tx;
            bf16x8 bz = *(const bf16x8*)(smem + ty*4160 + (px << 5) + ((quad & 1) << 4));
            #pragma unroll
            for (int i = 0; i < 4; ++i)
                acc1[i][j] = __builtin_amdgcn_mfma_f32_16x16x32_bf16(aw[i], bz, acc1[i][j], 0, 0, 0);
        }
    }
    {
        #pragma unroll
        for (int i = 0; i < 4; ++i) {
            float4v bv = *(const float4v*)(b1 + i*16 + quad*4);
            int cc = 2*i + (quad >> 1);
            int wo = ((quad & 1) << 3);
            #pragma unroll
            for (int j = 0; j < 2; ++j) {
                int px = j*16 + l15;
                int base = (px << 7) + ((cc ^ (px & 7)) << 4) + wo;
                *(int*)(ht + base)     = pack2(f2bf(fmaxf(acc1[i][j][0] + bv[0], 0.f)),
                                               f2bf(fmaxf(acc1[i][j][1] + bv[1], 0.f)));
                *(int*)(ht + base + 4) = pack2(f2bf(fmaxf(acc1[i][j][2] + bv[2], 0.f)),
                                               f2bf(fmaxf(acc1[i][j][3] + bv[3], 0.f)));
            }
        }
    }
    float4v acc2[4][2];
    #pragma unroll
    for (int i = 0; i < 4; ++i)
        #pragma unroll
        for (int j = 0; j < 2; ++j) acc2[i][j] = z4;

    #pragma unroll
    for (int s = 0; s < 2; ++s) {
        const char* ap = W2g + (((s*4 + quad)*64 + l15) << 4);
        bf16x8 aw[4];
        #pragma unroll
        for (int i = 0; i < 4; ++i)
            aw[i] = *(const bf16x8*)(ap + (i << 8));
        #pragma unroll
        for (int j = 0; j < 2; ++j) {
            int px = j*16 + l15;
            bf16x8 bh = *(const bf16x8*)(ht + (px << 7) + (((s*4 + quad) ^ (px & 7)) << 4));
            #pragma unroll
            for (int i = 0; i < 4; ++i)
                acc2[i][j] = __builtin_amdgcn_mfma_f32_16x16x32_bf16(aw[i], bh, acc2[i][j], 0, 0, 0);
        }
    }
    {
        #pragma unroll
        for (int i = 0; i < 4; ++i) {
            float4v bv = *(const float4v*)(b2 + i*16 + quad*4);
            int cc = 2*i + (quad >> 1);
            int wo = ((quad & 1) << 3);
            #pragma unroll
            for (int j = 0; j < 2; ++j) {
                int px = j*16 + l15;
                int base = (px << 7) + ((cc ^ (px & 7)) << 4) + wo;
                *(int*)(ht + base)     = pack2(f2bf(fmaxf(acc2[i][j][0] + bv[0], 0.f)),
                                               f2bf(fmaxf(acc2[i][j][1] + bv[1], 0.f)));
                *(int*)(ht + base + 4) = pack2(f2bf(fmaxf(acc2[i][j][2] + bv[2], 0.f)),
                                               f2bf(fmaxf(acc2[i][j][3] + bv[3], 0.f)));
            }
        }
    }
    char* dst = h2p + ((size_t)(b*130 + y + 1)*130 + 1 + pxb)*128;
    #pragma unroll
    for (int u = 0; u < 4; ++u) {
        int q = (u << 6) + lane;
        int px = q >> 3, cc = q & 7;
        int4v v = *(const int4v*)(ht + (px << 7) + ((cc ^ (px & 7)) << 4));
        *(int4v*)(dst + (px << 7) + (cc << 4)) = v;
    }
}

// ---------------------------------------------------------------------------
// RQS transform for one pixel given 23 params + x value. Returns y, adds lad.
// ---------------------------------------------------------------------------
static __device__ __forceinline__ float rqs_eval(
    const float* __restrict__ pa, float xin, bool frozen, float& ldsum)
{
    float xa = frozen ? 0.f : xin;
    float xf = frozen ? xin : 0.f;
    float xc = fminf(fmaxf(xa, -3.f), 3.f);
    bool inside = (xa >= -3.f) && (xa <= 3.f);

    float mw = pa[0];
    #pragma unroll
    for (int j = 1; j < 8; ++j) mw = fmaxf(mw, pa[j]);
    float ew[8]; float sw = 0.f;
    #pragma unroll
    for (int j = 0; j < 8; ++j) { ew[j] = __expf(pa[j] - mw); sw += ew[j]; }
    float Aw = 0.992f / sw;
    float run = 0.f, cwl = -3.f, icw = -3.f, iwid = 1.f;
    int idx = 0;
    #pragma unroll
    for (int j = 0; j < 8; ++j) {
        float wj = fmaf(Aw, ew[j], 0.001f);
        run += wj;
        float cwr = (j == 7) ? 3.f : fmaf(6.f, run, -3.f);
        if (xc >= cwl) { icw = cwl; iwid = cwr - cwl; idx = j; }
        cwl = cwr;
    }
    float mh = pa[8];
    #pragma unroll
    for (int j = 9; j < 16; ++j) mh = fmaxf(mh, pa[j]);
    float eh[8]; float sh = 0.f;
    #pragma unroll
    for (int j = 0; j < 8; ++j) { eh[j] = __expf(pa[8 + j] - mh); sh += eh[j]; }
    float Ah = 0.992f / sh;
    run = 0.f;
    float chl = -3.f, ich = 0.f, ihei = 1.f;
    #pragma unroll
    for (int j = 0; j < 8; ++j) {
        float hj = fmaf(Ah, eh[j], 0.001f);
        run += hj;
        float chr = (j == 7) ? 3.f : fmaf(6.f, run, -3.f);
        if (j == idx) { ich = chl; ihei = chr - chl; }
        chl = chr;
    }
    float v0 = 0.f, v1 = 0.f;
    bool h0 = false, h1 = false;
    #pragma unroll
    for (int j = 1; j < 8; ++j) {
        float v = pa[15 + j];
        if (j == idx)     { v0 = v; h0 = true; }
        if (j == idx + 1) { v1 = v; h1 = true; }
    }
    float sp0 = (v0 > 15.f) ? v0 : __logf(1.f + __expf(v0));
    float sp1 = (v1 > 15.f) ? v1 : __logf(1.f + __expf(v1));
    float d0 = h0 ? (0.001f + sp0) : 1.f;
    float d1 = h1 ? (0.001f + sp1) : 1.f;

    float dl = ihei / iwid;
    float th = (xc - icw) / iwid;
    float omt = 1.f - th;
    float t1 = th * omt;
    float num = ihei * (dl*th*th + d0*t1);
    float den = dl + (d0 + d1 - 2.f*dl)*t1;
    float yv = ich + num/den;
    float dnum = dl*dl*(d1*th*th + 2.f*dl*t1 + d0*omt*omt);
    float lad = __logf(dnum) - 2.f*__logf(den);

    ldsum += inside ? lad : 0.f;
    return xf + (inside ? yv : xa);
}

// ---------------------------------------------------------------------------
// conv3 (3x3, 64 -> 276 pad 288) fused with RQS — HYBRID operand paths.
// R14: staging rows trimmed 72->66 px (exactly the touched window) -> LDS
// 25344 B -> 6 blocks/CU (was 27648 -> 4-5). Direct atomics to ldout.
// ---------------------------------------------------------------------------
__global__ __launch_bounds__(192, 4) void conv3_rqs_kernel(
    const char* __restrict__ h2p, const char* __restrict__ W3g,
    const float* __restrict__ b3, const float* __restrict__ x,
    float* __restrict__ out, float* __restrict__ ldout)
{
    __shared__ __align__(16) char smem[25344];
    // staging: 3 rows x 66 px x 128 B | epilogue (aliased): 32 px x 148 floats
    int t = threadIdx.x;
    int lane = t & 63, w = t >> 6;     // w = col-group of 48 (0..2)
    int l15 = lane & 15, quad = lane >> 4;
    int bid = blockIdx.x;
    int b = bid & 15;
    int r = bid >> 4;                  // 0..511
    int chalf = r & 1;
    int h = (r >> 1) & 1;
    int y = r >> 2;

    // ---- stage A once: 1584 chunks (3 rows x 66 px x 8) over 192 thr ----
    const char* h2pb = h2p + (size_t)(b*130)*130*128;
    int colLo = h*64;
    #pragma unroll
    for (int ii = 0; ii < 9; ++ii) {
        int q = t + ii*192;
        if (q < 1584) {
            int row = q / 528;
            int rem = q - row*528;
            int p = rem >> 3, cs = rem & 7;
            int cg = cs ^ (p & 7);
            const char* g = h2pb + (((y + row)*130 + colLo + p) << 7) + (cg << 4);
            async_cp16(g, smem + (unsigned)__builtin_amdgcn_readfirstlane(
                                     (w << 10) + ii*3072) + (lane << 4));
        }
    }
    __syncthreads();

    const float4v z4 = {0.f,0.f,0.f,0.f};
    float4v acc[4][3];
    #pragma unroll
    for (int i = 0; i < 4; ++i)
        #pragma unroll
        for (int j = 0; j < 3; ++j) acc[i][j] = z4;

    int bcol = chalf*144 + w*48 + l15;     // global B col for j=0

    for (int tap = 0; tap < 9; ++tap) {
        int ty = (tap*11) >> 5;
        int tx = tap - 3*ty;
        int rowbase = ty*8448;
        #pragma unroll
        for (int ks = 0; ks < 2; ++ks) {
            bf16x8 av[4];
            #pragma unroll
            for (int i = 0; i < 4; ++i) {
                int p = i*16 + l15 + tx;
                av[i] = *(const bf16x8*)(smem + rowbase + (p << 7)
                         + ((((ks << 2) + quad) ^ (p & 7)) << 4));
            }
            const char* bp = W3g
                + ((((tap*2 + ks)*4 + quad)*288 + bcol) << 4);
            #pragma unroll
            for (int j = 0; j < 3; ++j) {
                bf16x8 bv = *(const bf16x8*)(bp + (j << 8));
                #pragma unroll
                for (int i = 0; i < 4; ++i)
                    acc[i][j] = __builtin_amdgcn_mfma_f32_16x16x32_bf16(av[i], bv, acc[i][j], 0, 0, 0);
            }
        }
    }
    __syncthreads();   // all staged-A reads done -> alias LDS for epilogue

    // -------- epilogue: 2 rounds (32 px x 144 col), 1 task/thread ----------
    float* scr = (float*)smem;   // [32 px][148]
    float ldsum = 0.f;
    int pxl = t & 31;
    int chl = t >> 5;            // 0..5
    int ch = chalf*6 + chl;
    const float* bb3 = b3 + ch*23;

    #pragma unroll
    for (int rnd = 0; rnd < 2; ++rnd) {
        #pragma unroll
        for (int i2 = 0; i2 < 2; ++i2) {
            int i = rnd*2 + i2;
            #pragma unroll
            for (int j = 0; j < 3; ++j)
                #pragma unroll
                for (int rr = 0; rr < 4; ++rr)
                    scr[(i2*16 + quad*4 + rr)*148 + w*48 + j*16 + l15] = acc[i][j][rr];
        }
        __syncthreads();
        const float* P = scr + pxl*148 + chl*24;
        float pa[23];
        {
            float pr[24];
            *(float4v*)&pr[0]  = *(const float4v*)(P);
            *(float4v*)&pr[4]  = *(const float4v*)(P + 4);
            *(float4v*)&pr[8]  = *(const float4v*)(P + 8);
            *(float4v*)&pr[12] = *(const float4v*)(P + 12);
            *(float4v*)&pr[16] = *(const float4v*)(P + 16);
            *(float4v*)&pr[20] = *(const float4v*)(P + 20);
            #pragma unroll
            for (int j = 0; j < 23; ++j) pa[j] = pr[j] + bb3[j];
        }
        int pxg = h*64 + rnd*32 + pxl;
        int gidx = ((b*12 + ch) << 14) + (y << 7) + pxg;
        float xin = x[gidx];
        bool frozen = ((y + pxg) & 1) == 1;
        out[gidx] = rqs_eval(pa, xin, frozen, ldsum);
        __syncthreads();
    }
    #pragma unroll
    for (int off = 32; off > 0; off >>= 1)
        ldsum += __shfl_down(ldsum, off, 64);
    if (lane == 0) atomicAdd(ldout + b, ldsum);
}

// ---------------------------------------------------------------------------
extern "C" void kernel_launch(void* const* d_in, const int* in_sizes, int n_in,
                              void* d_out, int out_size, void* d_ws, size_t ws_size,
                              hipStream_t stream)
{
    (void)in_sizes; (void)n_in; (void)out_size; (void)ws_size;
    const float* x    = (const float*)d_in[0];
    const float* ld   = (const float*)d_in[1];
    const float* cond = (const float*)d_in[2];
    const float* W1   = (const float*)d_in[3];
    const float* b1   = (const float*)d_in[4];
    const float* W2   = (const float*)d_in[5];
    const float* b2   = (const float*)d_in[6];
    const float* W3   = (const float*)d_in[7];
    const float* b3   = (const float*)d_in[8];
    float* out = (float*)d_out;
    char* ws = (char*)d_ws;

    short* zp     = (short*)(ws);              //  8,652,800 B
    char*  h2p    = ws + 8652800;              // 34,611,200 B
    short* W1g    = (short*)(ws + 43264000);   //     20,480 B
    short* W2g    = (short*)(ws + 43284480);   //      8,192 B
    short* W3g    = (short*)(ws + 43292672);   //    331,776 B
    float* ldout  = out + 12*HW*16;

    prep_weights<<<dim3(256), dim3(256), 0, stream>>>(
        W1, W2, W3, W1g, W2g, W3g, h2p);
    pack_z<<<dim3(1057), dim3(256), 0, stream>>>(x, cond, ld, zp, ldout);
    conv12_kernel<<<dim3(2048), dim3(256), 0, stream>>>(
        (const char*)zp, (const char*)W1g, (const char*)W2g, b1, b2, h2p);
    conv3_rqs_kernel<<<dim3(8192), dim3(192), 0, stream>>>(
        (const char*)h2p, (const char*)W3g, b3, x, out, ldout);
}

// Round 15
// 198.467 us; speedup vs baseline: 2.1465x; 2.1465x over previous
//
#include <hip/hip_runtime.h>

#define HW (128*128)

typedef __bf16 bf16x8 __attribute__((ext_vector_type(8)));
typedef float  float4v __attribute__((ext_vector_type(4)));
typedef int    int4v   __attribute__((ext_vector_type(4)));

static __device__ __forceinline__ short f2bf(float f) {
    unsigned u = __float_as_uint(f);
    unsigned r = (u + 0x7FFFu + ((u >> 16) & 1u)) >> 16;
    return (short)(r & 0xFFFFu);
}
static __device__ __forceinline__ int pack2(short a, short b) {
    return (int)((unsigned short)a | ((unsigned)(unsigned short)b << 16));
}
// async global->LDS, 16B per lane; LDS dest = wave-uniform base + lane*16
static __device__ __forceinline__ void async_cp16(const void* g, void* l) {
    __builtin_amdgcn_global_load_lds(
        (const __attribute__((address_space(1))) unsigned int*)g,
        (__attribute__((address_space(3))) unsigned int*)l, 16, 0, 0);
}

// ---------------------------------------------------------------------------
// prep: weight repacks + h2p halo zeroing (unchanged from R13).
// ---------------------------------------------------------------------------
__global__ __launch_bounds__(256) void prep_weights(
    const float* __restrict__ W1, const float* __restrict__ W2,
    const float* __restrict__ W3,
    short* __restrict__ W1g, short* __restrict__ W2g, short* __restrict__ W3g,
    char* __restrict__ h2p)
{
    int tid = blockIdx.x * 256 + threadIdx.x;
    int stride = gridDim.x * 256;
    for (int i = tid; i < 10240; i += stride) {
        int e = i & 7, ch = (i >> 3) & 63, sq = i >> 9;   // sq 0..19
        int s = sq >> 2, quad = sq & 3;
        int k = s*32 + quad*8 + e;
        int tap = k >> 4, ci = k & 15;
        float v = 0.f;
        if (tap < 9) {
            int ky = (tap*11) >> 5; int kx = tap - 3*ky;
            v = W1[((ch*16 + ci)*3 + ky)*3 + kx];
        }
        W1g[i] = f2bf(v);
    }
    for (int i = tid; i < 4096; i += stride) {
        int e = i & 7, ch = (i >> 3) & 63, sq = i >> 9;   // sq 0..7
        int s = sq >> 2, quad = sq & 3;
        int k = s*32 + quad*8 + e;
        W2g[i] = f2bf(W2[ch*64 + k]);
    }
    // W3g: flat i = ((tap*8 + ks*4 + quad)*288 + n)*8 + e
    for (int i = tid; i < 165888; i += stride) {
        int e = i & 7;
        int n = (i >> 3) % 288;
        int r2 = i / 2304;
        int quad = r2 & 3;
        int ks = (r2 >> 2) & 1;
        int tap = r2 >> 3;
        int ch = n / 24, jj = n - 24*ch;
        int kk = ks*32 + quad*8 + e;
        float v = 0.f;
        if (jj < 23) v = W3[((ch*23 + jj)*64 + kk)*9 + tap];
        W3g[i] = f2bf(v);
    }
    // h2p halo zero: 16 batches x 516 border px x 8 chunks
    for (int i = tid; i < 16*516*8; i += stride) {
        int cchunk = i & 7, pxi = (i >> 3) % 516, b = i / (516*8);
        int yy, xx;
        if (pxi < 130)      { yy = 0;   xx = pxi; }
        else if (pxi < 260) { yy = 129; xx = pxi - 130; }
        else if (pxi < 388) { yy = pxi - 260 + 1; xx = 0; }
        else                { yy = pxi - 388 + 1; xx = 129; }
        int4v zz = {0,0,0,0};
        *(int4v*)(h2p + (size_t)((b*130 + yy)*130 + xx)*128 + cchunk*16) = zz;
    }
}

// ---------------------------------------------------------------------------
// pack z with 1-px halo; zero logdet partial slots.
// ---------------------------------------------------------------------------
__global__ __launch_bounds__(256) void pack_z(
    const float* __restrict__ x, const float* __restrict__ cond,
    short* __restrict__ zp, float* __restrict__ ldslots)
{
    int id = blockIdx.x * 256 + threadIdx.x;
    if (id < 1024) ldslots[id] = 0.f;
    if (id >= 16*130*130) return;
    int b = id / 16900;
    int rem = id - b*16900;
    int yy = rem / 130;
    int xx = rem - yy*130;
    short vs[16];
    #pragma unroll
    for (int c = 0; c < 16; ++c) vs[c] = 0;
    if (yy >= 1 && yy <= 128 && xx >= 1 && xx <= 128) {
        int pix = (yy - 1)*128 + (xx - 1);
        bool frozen = ((yy + xx) & 1) == 1;
        #pragma unroll
        for (int c = 0; c < 12; ++c)
            vs[c] = f2bf(frozen ? x[(b*12 + c)*HW + pix] : 0.f);
        #pragma unroll
        for (int c = 0; c < 4; ++c)
            vs[12 + c] = f2bf(cond[(b*4 + c)*HW + pix]);
    }
    int4v lo = { pack2(vs[0],vs[1]),  pack2(vs[2],vs[3]),
                 pack2(vs[4],vs[5]),  pack2(vs[6],vs[7]) };
    int4v hi = { pack2(vs[8],vs[9]),  pack2(vs[10],vs[11]),
                 pack2(vs[12],vs[13]),pack2(vs[14],vs[15]) };
    *(int4v*)(zp + id*16)     = lo;
    *(int4v*)(zp + id*16 + 8) = hi;
}

// ---------------------------------------------------------------------------
// fused conv1 (3x3, 16->64) + conv2 (1x1, 64->64) — hybrid paths, ONE barrier.
// (Unchanged from R13.)
// ---------------------------------------------------------------------------
__global__ __launch_bounds__(256, 4) void conv12_kernel(
    const char* __restrict__ zp, const char* __restrict__ W1g,
    const char* __restrict__ W2g,
    const float* __restrict__ b1, const float* __restrict__ b2,
    char* __restrict__ h2p)
{
    __shared__ __align__(16) char smem[28928];
    int t = threadIdx.x;
    int lane = t & 63, w = t >> 6;
    int l15 = lane & 15, quad = lane >> 4;
    int bid = blockIdx.x;
    int b = bid & 15, y = bid >> 4;
    int pxb = w << 5;

    const char* zb = (const char*)zp + ((size_t)(b*16900) + (size_t)y*130)*32;
    #pragma unroll
    for (int ii = 0; ii < 4; ++ii) {
        int q = t + ii*256;
        if (q < 780)
            async_cp16(zb + (q << 4),
                smem + (unsigned)__builtin_amdgcn_readfirstlane(
                            ((w << 6) + ii*256) << 4) + (lane << 4));
    }
    __syncthreads();

    const float4v z4 = {0.f,0.f,0.f,0.f};
    char* ht = smem + 12544 + (w << 12);

    float4v acc1[4][2];
    #pragma unroll
    for (int i = 0; i < 4; ++i)
        #pragma unroll
        for (int j = 0; j < 2; ++j) acc1[i][j] = z4;

    for (int s = 0; s < 5; ++s) {
        const char* ap = W1g + (((s*4 + quad)*64 + l15) << 4);
        bf16x8 aw[4];
        #pragma unroll
        for (int i = 0; i < 4; ++i)
            aw[i] = *(const bf16x8*)(ap + (i << 8));
        int tap = 2*s + (quad >> 1);
        int tapc = tap > 8 ? 8 : tap;
        int ty = (tapc*11) >> 5;
        int tx = tapc - 3*ty;
        #pragma unroll
        for (int j = 0; j < 2; ++j) {
            int px = pxb + j*16 + l15 + tx;
            bf16x8 bz = *(const bf16x8*)(smem + ty*4160 + (px << 5) + ((quad & 1) << 4));
            #pragma unroll
            for (int i = 0; i < 4; ++i)
                acc1[i][j] = __builtin_amdgcn_mfma_f32_16x16x32_bf16(aw[i], bz, acc1[i][j], 0, 0, 0);
        }
    }
    {
        #pragma unroll
        for (int i = 0; i < 4; ++i) {
            float4v bv = *(const float4v*)(b1 + i*16 + quad*4);
            int cc = 2*i + (quad >> 1);
            int wo = ((quad & 1) << 3);
            #pragma unroll
            for (int j = 0; j < 2; ++j) {
                int px = j*16 + l15;
                int base = (px << 7) + ((cc ^ (px & 7)) << 4) + wo;
                *(int*)(ht + base)     = pack2(f2bf(fmaxf(acc1[i][j][0] + bv[0], 0.f)),
                                               f2bf(fmaxf(acc1[i][j][1] + bv[1], 0.f)));
                *(int*)(ht + base + 4) = pack2(f2bf(fmaxf(acc1[i][j][2] + bv[2], 0.f)),
                                               f2bf(fmaxf(acc1[i][j][3] + bv[3], 0.f)));
            }
        }
    }
    float4v acc2[4][2];
    #pragma unroll
    for (int i = 0; i < 4; ++i)
        #pragma unroll
        for (int j = 0; j < 2; ++j) acc2[i][j] = z4;

    #pragma unroll
    for (int s = 0; s < 2; ++s) {
        const char* ap = W2g + (((s*4 + quad)*64 + l15) << 4);
        bf16x8 aw[4];
        #pragma unroll
        for (int i = 0; i < 4; ++i)
            aw[i] = *(const bf16x8*)(ap + (i << 8));
        #pragma unroll
        for (int j = 0; j < 2; ++j) {
            int px = j*16 + l15;
            bf16x8 bh = *(const bf16x8*)(ht + (px << 7) + (((s*4 + quad) ^ (px & 7)) << 4));
            #pragma unroll
            for (int i = 0; i < 4; ++i)
                acc2[i][j] = __builtin_amdgcn_mfma_f32_16x16x32_bf16(aw[i], bh, acc2[i][j], 0, 0, 0);
        }
    }
    {
        #pragma unroll
        for (int i = 0; i < 4; ++i) {
            float4v bv = *(const float4v*)(b2 + i*16 + quad*4);
            int cc = 2*i + (quad >> 1);
            int wo = ((quad & 1) << 3);
            #pragma unroll
            for (int j = 0; j < 2; ++j) {
                int px = j*16 + l15;
                int base = (px << 7) + ((cc ^ (px & 7)) << 4) + wo;
                *(int*)(ht + base)     = pack2(f2bf(fmaxf(acc2[i][j][0] + bv[0], 0.f)),
                                               f2bf(fmaxf(acc2[i][j][1] + bv[1], 0.f)));
                *(int*)(ht + base + 4) = pack2(f2bf(fmaxf(acc2[i][j][2] + bv[2], 0.f)),
                                               f2bf(fmaxf(acc2[i][j][3] + bv[3], 0.f)));
            }
        }
    }
    char* dst = h2p + ((size_t)(b*130 + y + 1)*130 + 1 + pxb)*128;
    #pragma unroll
    for (int u = 0; u < 4; ++u) {
        int q = (u << 6) + lane;
        int px = q >> 3, cc = q & 7;
        int4v v = *(const int4v*)(ht + (px << 7) + ((cc ^ (px & 7)) << 4));
        *(int4v*)(dst + (px << 7) + (cc << 4)) = v;
    }
}

// ---------------------------------------------------------------------------
// RQS transform for one pixel given 23 params + x value. Returns y, adds lad.
// ---------------------------------------------------------------------------
static __device__ __forceinline__ float rqs_eval(
    const float* __restrict__ pa, float xin, bool frozen, float& ldsum)
{
    float xa = frozen ? 0.f : xin;
    float xf = frozen ? xin : 0.f;
    float xc = fminf(fmaxf(xa, -3.f), 3.f);
    bool inside = (xa >= -3.f) && (xa <= 3.f);

    float mw = pa[0];
    #pragma unroll
    for (int j = 1; j < 8; ++j) mw = fmaxf(mw, pa[j]);
    float ew[8]; float sw = 0.f;
    #pragma unroll
    for (int j = 0; j < 8; ++j) { ew[j] = __expf(pa[j] - mw); sw += ew[j]; }
    float Aw = 0.992f / sw;
    float run = 0.f, cwl = -3.f, icw = -3.f, iwid = 1.f;
    int idx = 0;
    #pragma unroll
    for (int j = 0; j < 8; ++j) {
        float wj = fmaf(Aw, ew[j], 0.001f);
        run += wj;
        float cwr = (j == 7) ? 3.f : fmaf(6.f, run, -3.f);
        if (xc >= cwl) { icw = cwl; iwid = cwr - cwl; idx = j; }
        cwl = cwr;
    }
    float mh = pa[8];
    #pragma unroll
    for (int j = 9; j < 16; ++j) mh = fmaxf(mh, pa[j]);
    float eh[8]; float sh = 0.f;
    #pragma unroll
    for (int j = 0; j < 8; ++j) { eh[j] = __expf(pa[8 + j] - mh); sh += eh[j]; }
    float Ah = 0.992f / sh;
    run = 0.f;
    float chl = -3.f, ich = 0.f, ihei = 1.f;
    #pragma unroll
    for (int j = 0; j < 8; ++j) {
        float hj = fmaf(Ah, eh[j], 0.001f);
        run += hj;
        float chr = (j == 7) ? 3.f : fmaf(6.f, run, -3.f);
        if (j == idx) { ich = chl; ihei = chr - chl; }
        chl = chr;
    }
    float v0 = 0.f, v1 = 0.f;
    bool h0 = false, h1 = false;
    #pragma unroll
    for (int j = 1; j < 8; ++j) {
        float v = pa[15 + j];
        if (j == idx)     { v0 = v; h0 = true; }
        if (j == idx + 1) { v1 = v; h1 = true; }
    }
    float sp0 = (v0 > 15.f) ? v0 : __logf(1.f + __expf(v0));
    float sp1 = (v1 > 15.f) ? v1 : __logf(1.f + __expf(v1));
    float d0 = h0 ? (0.001f + sp0) : 1.f;
    float d1 = h1 ? (0.001f + sp1) : 1.f;

    float dl = ihei / iwid;
    float th = (xc - icw) / iwid;
    float omt = 1.f - th;
    float t1 = th * omt;
    float num = ihei * (dl*th*th + d0*t1);
    float den = dl + (d0 + d1 - 2.f*dl)*t1;
    float yv = ich + num/den;
    float dnum = dl*dl*(d1*th*th + 2.f*dl*t1 + d0*omt*omt);
    float lad = __logf(dnum) - 2.f*__logf(den);

    ldsum += inside ? lad : 0.f;
    return xf + (inside ? yv : xa);
}

// ---------------------------------------------------------------------------
// conv3 (3x3, 64 -> 276 pad 288) fused with RQS — HYBRID operand paths.
// R15: 66-px staging rows (25344 B LDS) kept from R14; atomics reverted to
// the 1024-slot ldslots spread (R14's 16-hot-address direct atomics cost
// +230 µs of serialized RMW tail — G12 lesson).
// ---------------------------------------------------------------------------
__global__ __launch_bounds__(192, 4) void conv3_rqs_kernel(
    const char* __restrict__ h2p, const char* __restrict__ W3g,
    const float* __restrict__ b3, const float* __restrict__ x,
    float* __restrict__ out, float* __restrict__ ldslots)
{
    __shared__ __align__(16) char smem[25344];
    // staging: 3 rows x 66 px x 128 B | epilogue (aliased): 32 px x 148 floats
    int t = threadIdx.x;
    int lane = t & 63, w = t >> 6;     // w = col-group of 48 (0..2)
    int l15 = lane & 15, quad = lane >> 4;
    int bid = blockIdx.x;
    int b = bid & 15;
    int r = bid >> 4;                  // 0..511
    int chalf = r & 1;
    int h = (r >> 1) & 1;
    int y = r >> 2;

    // ---- stage A once: 1584 chunks (3 rows x 66 px x 8) over 192 thr ----
    const char* h2pb = h2p + (size_t)(b*130)*130*128;
    int colLo = h*64;
    #pragma unroll
    for (int ii = 0; ii < 9; ++ii) {
        int q = t + ii*192;
        if (q < 1584) {
            int row = q / 528;
            int rem = q - row*528;
            int p = rem >> 3, cs = rem & 7;
            int cg = cs ^ (p & 7);
            const char* g = h2pb + (((y + row)*130 + colLo + p) << 7) + (cg << 4);
            async_cp16(g, smem + (unsigned)__builtin_amdgcn_readfirstlane(
                                     (w << 10) + ii*3072) + (lane << 4));
        }
    }
    __syncthreads();

    const float4v z4 = {0.f,0.f,0.f,0.f};
    float4v acc[4][3];
    #pragma unroll
    for (int i = 0; i < 4; ++i)
        #pragma unroll
        for (int j = 0; j < 3; ++j) acc[i][j] = z4;

    int bcol = chalf*144 + w*48 + l15;     // global B col for j=0

    for (int tap = 0; tap < 9; ++tap) {
        int ty = (tap*11) >> 5;
        int tx = tap - 3*ty;
        int rowbase = ty*8448;
        #pragma unroll
        for (int ks = 0; ks < 2; ++ks) {
            bf16x8 av[4];
            #pragma unroll
            for (int i = 0; i < 4; ++i) {
                int p = i*16 + l15 + tx;
                av[i] = *(const bf16x8*)(smem + rowbase + (p << 7)
                         + ((((ks << 2) + quad) ^ (p & 7)) << 4));
            }
            const char* bp = W3g
                + ((((tap*2 + ks)*4 + quad)*288 + bcol) << 4);
            #pragma unroll
            for (int j = 0; j < 3; ++j) {
                bf16x8 bv = *(const bf16x8*)(bp + (j << 8));
                #pragma unroll
                for (int i = 0; i < 4; ++i)
                    acc[i][j] = __builtin_amdgcn_mfma_f32_16x16x32_bf16(av[i], bv, acc[i][j], 0, 0, 0);
            }
        }
    }
    __syncthreads();   // all staged-A reads done -> alias LDS for epilogue

    // -------- epilogue: 2 rounds (32 px x 144 col), 1 task/thread ----------
    float* scr = (float*)smem;   // [32 px][148]
    float ldsum = 0.f;
    int pxl = t & 31;
    int chl = t >> 5;            // 0..5
    int ch = chalf*6 + chl;
    const float* bb3 = b3 + ch*23;

    #pragma unroll
    for (int rnd = 0; rnd < 2; ++rnd) {
        #pragma unroll
        for (int i2 = 0; i2 < 2; ++i2) {
            int i = rnd*2 + i2;
            #pragma unroll
            for (int j = 0; j < 3; ++j)
                #pragma unroll
                for (int rr = 0; rr < 4; ++rr)
                    scr[(i2*16 + quad*4 + rr)*148 + w*48 + j*16 + l15] = acc[i][j][rr];
        }
        __syncthreads();
        const float* P = scr + pxl*148 + chl*24;
        float pa[23];
        {
            float pr[24];
            *(float4v*)&pr[0]  = *(const float4v*)(P);
            *(float4v*)&pr[4]  = *(const float4v*)(P + 4);
            *(float4v*)&pr[8]  = *(const float4v*)(P + 8);
            *(float4v*)&pr[12] = *(const float4v*)(P + 12);
            *(float4v*)&pr[16] = *(const float4v*)(P + 16);
            *(float4v*)&pr[20] = *(const float4v*)(P + 20);
            #pragma unroll
            for (int j = 0; j < 23; ++j) pa[j] = pr[j] + bb3[j];
        }
        int pxg = h*64 + rnd*32 + pxl;
        int gidx = ((b*12 + ch) << 14) + (y << 7) + pxg;
        float xin = x[gidx];
        bool frozen = ((y + pxg) & 1) == 1;
        out[gidx] = rqs_eval(pa, xin, frozen, ldsum);
        __syncthreads();
    }
    #pragma unroll
    for (int off = 32; off > 0; off >>= 1)
        ldsum += __shfl_down(ldsum, off, 64);
    if (lane == 0) atomicAdd(ldslots + b*64 + (r & 63), ldsum);
}

// ---------------------------------------------------------------------------
// final logdet reduce: 16 blocks x 64 lanes.
// ---------------------------------------------------------------------------
__global__ __launch_bounds__(64) void logdet_reduce(
    const float* __restrict__ ldslots, const float* __restrict__ ld_in,
    float* __restrict__ ldout)
{
    int b = blockIdx.x;
    int lane = threadIdx.x;
    float s = ldslots[b*64 + lane];
    #pragma unroll
    for (int off = 32; off > 0; off >>= 1)
        s += __shfl_down(s, off, 64);
    if (lane == 0) ldout[b] = ld_in[b] + s;
}

// ---------------------------------------------------------------------------
extern "C" void kernel_launch(void* const* d_in, const int* in_sizes, int n_in,
                              void* d_out, int out_size, void* d_ws, size_t ws_size,
                              hipStream_t stream)
{
    (void)in_sizes; (void)n_in; (void)out_size; (void)ws_size;
    const float* x    = (const float*)d_in[0];
    const float* ld   = (const float*)d_in[1];
    const float* cond = (const float*)d_in[2];
    const float* W1   = (const float*)d_in[3];
    const float* b1   = (const float*)d_in[4];
    const float* W2   = (const float*)d_in[5];
    const float* b2   = (const float*)d_in[6];
    const float* W3   = (const float*)d_in[7];
    const float* b3   = (const float*)d_in[8];
    float* out = (float*)d_out;
    char* ws = (char*)d_ws;

    short* zp     = (short*)(ws);              //  8,652,800 B
    char*  h2p    = ws + 8652800;              // 34,611,200 B
    short* W1g    = (short*)(ws + 43264000);   //     20,480 B
    short* W2g    = (short*)(ws + 43284480);   //      8,192 B
    short* W3g    = (short*)(ws + 43292672);   //    331,776 B
    float* ldslots= (float*)(ws + 43625472);   //      4,096 B
    float* ldout  = out + 12*HW*16;

    prep_weights<<<dim3(256), dim3(256), 0, stream>>>(
        W1, W2, W3, W1g, W2g, W3g, h2p);
    pack_z<<<dim3(1057), dim3(256), 0, stream>>>(x, cond, zp, ldslots);
    conv12_kernel<<<dim3(2048), dim3(256), 0, stream>>>(
        (const char*)zp, (const char*)W1g, (const char*)W2g, b1, b2, h2p);
    conv3_rqs_kernel<<<dim3(8192), dim3(192), 0, stream>>>(
        (const char*)h2p, (const char*)W3g, b3, x, out, ldslots);
    logdet_reduce<<<dim3(16), dim3(64), 0, stream>>>(ldslots, ld, ldout);
}